// Round 11
// baseline (250.197 us; speedup 1.0000x reference)
//
#include <hip/hip_runtime.h>

// B=16, Lk=2048, Lq=256, DIM=512, HEADS=8, d_k=64 — f32 I/O, bf16 MFMA internally.
// out = softmax((G@Wq+bq) heads @ L^T * scale) @ L, merge heads, @ Wo + bo
#define KSTR 72   // attn P-buffer row stride (shorts)

typedef __attribute__((ext_vector_type(8))) short short8;  // 8 bf16 (4 VGPRs)
typedef __attribute__((ext_vector_type(4))) float f32x4;

#define EXP2F(x) __builtin_amdgcn_exp2f(x)

__device__ __forceinline__ unsigned short f2bf(float f) {   // RNE f32->bf16
    union { float f; unsigned u; } v; v.f = f;
    unsigned r = v.u + 0x7fff + ((v.u >> 16) & 1);
    return (unsigned short)(r >> 16);
}
__device__ __forceinline__ unsigned pk2(float a, float b) {
    return (unsigned)f2bf(a) | ((unsigned)f2bf(b) << 16);
}

// ---- merged prep: blocks [0,4096) do conv_L; blocks [4096,4352) do conv_W.
__global__ __launch_bounds__(256) void conv_prep(const float* __restrict__ Lmat,
                                                 const float* __restrict__ Wq,
                                                 const float* __restrict__ Wo,
                                                 unsigned short* __restrict__ KF,
                                                 unsigned short* __restrict__ VF,
                                                 unsigned short* __restrict__ WqF,
                                                 unsigned short* __restrict__ WoF) {
    const int tid = threadIdx.x;
    if (blockIdx.x >= 4096) {
        const int idx = blockIdx.x - 4096;            // [0,256)
        const float* W = (idx >> 7) ? Wo : Wq;
        unsigned short* WF = (idx >> 7) ? WoF : WqF;
        int g = (idx & 127) * 256 + tid;              // [0, 32768)
        int lane = g & 63, ntg = (g >> 6) & 31, kt = g >> 11;
        int c = lane & 15, quad = lane >> 4;
        const float* wp = W + (size_t)(32 * kt + 8 * quad) * 512 + 16 * ntg + c;
        float v[8];
        #pragma unroll
        for (int j = 0; j < 8; j++) v[j] = wp[(size_t)j * 512];
        uint4 u;
        u.x = pk2(v[0], v[1]); u.y = pk2(v[2], v[3]);
        u.z = pk2(v[4], v[5]); u.w = pk2(v[6], v[7]);
        *(uint4*)(WF + (size_t)g * 8) = u;
        return;
    }
    __shared__ unsigned short KFs[4096];
    __shared__ unsigned short VFs[4096];
    const int blk = blockIdx.x;            // ((b*8+h)*32+t)
    const int t = blk & 31, h = (blk >> 5) & 7, b = blk >> 8;
    const int key = tid & 63, wv = tid >> 6;   // 16 d's per thread

    const float* src = Lmat + ((size_t)(b * 2048 + 64 * t + key)) * 512 + 64 * h + 16 * wv;
    float4 a0 = *(const float4*)src;
    float4 a1 = *(const float4*)(src + 4);
    float4 a2 = *(const float4*)(src + 8);
    float4 a3 = *(const float4*)(src + 12);
    float vals[16] = {a0.x, a0.y, a0.z, a0.w, a1.x, a1.y, a1.z, a1.w,
                      a2.x, a2.y, a2.z, a2.w, a3.x, a3.y, a3.z, a3.w};
    #pragma unroll
    for (int i = 0; i < 16; i++) {
        int d = 16 * wv + i;
        unsigned short bv = f2bf(vals[i]);
        KFs[((((key >> 4) * 2 + (d >> 5)) * 64) + ((d >> 3) & 3) * 16 + (key & 15)) * 8 + (d & 7)] = bv;
        VFs[((((d >> 4) * 2 + (key >> 5)) * 64) + ((key >> 3) & 3) * 16 + (d & 15)) * 8 + (key & 7)] = bv;
    }
    __syncthreads();
    size_t gbase = (size_t)blk * 4096 + tid * 16;
    *(uint4*)(KF + gbase)     = *(const uint4*)&KFs[tid * 16];
    *(uint4*)(KF + gbase + 8) = *(const uint4*)&KFs[tid * 16 + 8];
    *(uint4*)(VF + gbase)     = *(const uint4*)&VFs[tid * 16];
    *(uint4*)(VF + gbase + 8) = *(const uint4*)&VFs[tid * 16 + 8];
}

// ---- barrier-free gemm: C[M,512] = (A@W + bias)*oscale. No LDS, no syncs.
template<bool A_BF16, bool OUT_BF16>
__global__ __launch_bounds__(256, 2) void gemm_direct(const void* __restrict__ Ap,
                                                      const unsigned short* __restrict__ WF,
                                                      const float* __restrict__ bias,
                                                      void* __restrict__ Cp,
                                                      float oscale) {
    const int tid = threadIdx.x;
    const int wv = tid >> 6, lane = tid & 63;
    const int c = lane & 15, quad = lane >> 4;
    const int m0 = blockIdx.x * 64, n0 = blockIdx.y * 64;
    const int row = m0 + 16 * wv + c;

    f32x4 acc[4];
    #pragma unroll
    for (int nt = 0; nt < 4; nt++) acc[nt] = (f32x4){0.f, 0.f, 0.f, 0.f};

    #pragma unroll
    for (int kk = 0; kk < 16; kk++) {
        short8 af;
        if (A_BF16) {
            af = *(const short8*)((const unsigned short*)Ap + (size_t)row * 512 + 32 * kk + 8 * quad);
        } else {
            const float* ap = (const float*)Ap + (size_t)row * 512 + 32 * kk + 8 * quad;
            float4 x0 = *(const float4*)ap;
            float4 x1 = *(const float4*)(ap + 4);
            af[0] = (short)f2bf(x0.x); af[1] = (short)f2bf(x0.y);
            af[2] = (short)f2bf(x0.z); af[3] = (short)f2bf(x0.w);
            af[4] = (short)f2bf(x1.x); af[5] = (short)f2bf(x1.y);
            af[6] = (short)f2bf(x1.z); af[7] = (short)f2bf(x1.w);
        }
        #pragma unroll
        for (int nt = 0; nt < 4; nt++) {
            short8 bf = *(const short8*)(WF +
                (((size_t)kk * 32 + (n0 >> 4) + nt) * 64 + lane) * 8);
            acc[nt] = __builtin_amdgcn_mfma_f32_16x16x32_bf16(af, bf, acc[nt], 0, 0, 0);
        }
    }

    #pragma unroll
    for (int nt = 0; nt < 4; nt++) {
        float bv = bias[n0 + 16 * nt + c];
        #pragma unroll
        for (int r = 0; r < 4; r++) {
            float v = (acc[nt][r] + bv) * oscale;
            size_t idx = (size_t)(m0 + 16 * wv + 4 * quad + r) * 512 + n0 + 16 * nt + c;
            if (OUT_BF16) ((unsigned short*)Cp)[idx] = f2bf(v);
            else          ((float*)Cp)[idx] = v;
        }
    }
}

// ---- attn: round-7 structure with 8-WAVE blocks — double TLP, SAME traffic.
// Round-10 lesson: never trade K/V traffic for TLP (2x traffic = 1.25x slower).
// Here: 512 blocks x 512 threads; wave wv handles tiles wv,wv+8,wv+16,wv+24
// for ALL 4 q-groups (each K/V tile still loaded exactly once per block ->
// identical vmem traffic to round 7), but 16 waves/CU = 4 waves/SIMD (round 7:
// 2/SIMD, pipes only ~30% busy, rest both-waves-stalled on latency).
// Per-wave body identical to round 7 (compiled to 104 VGPR there) ->
// launch_bounds(512,4) caps at 128, no spill expected (tripwire: WRITE_SIZE).
// Epilogue: 2-stage additive fold (waves 4-7 dump, waves 0-3 add+dump, final
// round-7 merge by waves 0-3).
__global__ __launch_bounds__(512, 4) void attn_frag(const float* __restrict__ G,
                                                    const unsigned short* __restrict__ WqF,
                                                    const float* __restrict__ bq,
                                                    const unsigned short* __restrict__ KF,
                                                    const unsigned short* __restrict__ VF,
                                                    unsigned short* __restrict__ X,
                                                    float SCe) {
    // [0,18432) Pw[8][16*KSTR] | [18432,27648) Qs[64][72]  (loop phase)
    // [0,69632) Mrg[4][64][68] f32                         (merge overlay)
    __shared__ __align__(16) char shm[4 * 64 * 68 * 4];
    unsigned short (*Pw)[16 * KSTR] = (unsigned short (*)[16 * KSTR])shm;
    unsigned short (*Qs)[72] = (unsigned short (*)[72])(shm + 18432);
    float (*Mrg)[64][68] = (float (*)[64][68])shm;

    // swizzle: raw = xcd + 8*(qt + 4*grp); bh = grp*8 + xcd -> b=grp, h=xcd
    const int raw = blockIdx.x;
    const int h  = raw & 7;
    const int qt = (raw >> 3) & 3;
    const int b  = raw >> 5;
    const int tid = threadIdx.x;
    const int wv = tid >> 6, lane = tid & 63;
    const int c = lane & 15, quad = lane >> 4;
    const int n0 = h * 64;

    // ---- fused Q projection: waves 0-3 compute the 64-row Q tile
    if (wv < 4) {
        f32x4 qacc[4];
        #pragma unroll
        for (int nt = 0; nt < 4; nt++) qacc[nt] = (f32x4){0.f, 0.f, 0.f, 0.f};
        const float* gbase = G + ((size_t)(b * 256 + qt * 64 + 16 * wv + c)) * 512;
        #pragma unroll
        for (int kk = 0; kk < 16; kk++) {
            const float* ap = gbase + 32 * kk + 8 * quad;
            float4 x0 = *(const float4*)ap;
            float4 x1 = *(const float4*)(ap + 4);
            short8 af;
            af[0] = (short)f2bf(x0.x); af[1] = (short)f2bf(x0.y);
            af[2] = (short)f2bf(x0.z); af[3] = (short)f2bf(x0.w);
            af[4] = (short)f2bf(x1.x); af[5] = (short)f2bf(x1.y);
            af[6] = (short)f2bf(x1.z); af[7] = (short)f2bf(x1.w);
            #pragma unroll
            for (int nt = 0; nt < 4; nt++) {
                short8 bf = *(const short8*)(WqF +
                    (((size_t)kk * 32 + (n0 >> 4) + nt) * 64 + lane) * 8);
                qacc[nt] = __builtin_amdgcn_mfma_f32_16x16x32_bf16(af, bf, qacc[nt], 0, 0, 0);
            }
        }
        #pragma unroll
        for (int nt = 0; nt < 4; nt++) {
            float bv = bq[n0 + 16 * nt + c];
            #pragma unroll
            for (int r = 0; r < 4; r++)
                Qs[16 * wv + 4 * quad + r][16 * nt + c] =
                    f2bf((qacc[nt][r] + bv) * SCe);
        }
    }
    __syncthreads();

    short8 qa[4][2];   // all 64 q-rows: qgrp g = rows 16g..16g+15
    #pragma unroll
    for (int g = 0; g < 4; g++) {
        qa[g][0] = *(const short8*)&Qs[16 * g + c][8 * quad];
        qa[g][1] = *(const short8*)&Qs[16 * g + c][32 + 8 * quad];
    }
    // Qs and Pw are disjoint regions -> no second barrier needed.

    short8 ones;
    #pragma unroll
    for (int i = 0; i < 8; i++) ones[i] = (short)0x3F80;

    f32x4 oacc[4][4];
    #pragma unroll
    for (int g = 0; g < 4; g++)
        #pragma unroll
        for (int dt = 0; dt < 4; dt++) oacc[g][dt] = (f32x4){0.f, 0.f, 0.f, 0.f};
    f32x4 lacc[4];
    #pragma unroll
    for (int g = 0; g < 4; g++) lacc[g] = (f32x4){0.f, 0.f, 0.f, 0.f};

    const int swc = (c >> 3) & 1;
    const int swr = (quad >> 1) & 1;

    const unsigned short* kf = KF + ((size_t)((b * 8 + h) * 32)) * 4096 + lane * 8;
    const unsigned short* vf = VF + ((size_t)((b * 8 + h) * 32)) * 4096 + lane * 8;

    for (int i = 0; i < 4; i++) {
        const int T = wv + 8 * i;           // this wave's tile (8-way split-K)
        const unsigned short* kt = kf + (size_t)T * 4096;
        const unsigned short* vt = vf + (size_t)T * 4096;
        short8 kbuf[8], vbuf[8];
        #pragma unroll
        for (int f = 0; f < 8; f++) kbuf[f] = *(const short8*)(kt + f * 512);
        #pragma unroll
        for (int f = 0; f < 8; f++) vbuf[f] = *(const short8*)(vt + f * 512);

        #pragma unroll
        for (int g = 0; g < 4; g++) {
            f32x4 sacc[4];
            #pragma unroll
            for (int nt = 0; nt < 4; nt++) sacc[nt] = (f32x4){0.f, 0.f, 0.f, 0.f};
            __builtin_amdgcn_s_setprio(1);
            #pragma unroll
            for (int nt = 0; nt < 4; nt++)
                #pragma unroll
                for (int ks = 0; ks < 2; ks++)
                    sacc[nt] = __builtin_amdgcn_mfma_f32_16x16x32_bf16(
                        qa[g][ks], kbuf[nt * 2 + ks], sacc[nt], 0, 0, 0);
            __builtin_amdgcn_s_setprio(0);
            #pragma unroll
            for (int nt = 0; nt < 4; nt++)
                #pragma unroll
                for (int r = 0; r < 4; r++)
                    Pw[wv][(4 * quad + r) * KSTR + ((16 * nt + c) ^ (8 * swr))] =
                        f2bf(EXP2F(sacc[nt][r]));
            short8 pa0 = *(const short8*)&Pw[wv][c * KSTR + 8 * (quad ^ swc)];
            short8 pa1 = *(const short8*)&Pw[wv][c * KSTR + 32 + 8 * (quad ^ swc)];
            __builtin_amdgcn_s_setprio(1);
            #pragma unroll
            for (int dt = 0; dt < 4; dt++) {
                oacc[g][dt] = __builtin_amdgcn_mfma_f32_16x16x32_bf16(pa0, vbuf[dt * 2], oacc[g][dt], 0, 0, 0);
                oacc[g][dt] = __builtin_amdgcn_mfma_f32_16x16x32_bf16(pa1, vbuf[dt * 2 + 1], oacc[g][dt], 0, 0, 0);
            }
            lacc[g] = __builtin_amdgcn_mfma_f32_16x16x32_bf16(pa0, ones, lacc[g], 0, 0, 0);
            lacc[g] = __builtin_amdgcn_mfma_f32_16x16x32_bf16(pa1, ones, lacc[g], 0, 0, 0);
            __builtin_amdgcn_s_setprio(0);
        }
    }

    // ---- 2-stage additive fold (Mrg overlays Pw/Qs -> barrier first).
    __syncthreads();
    if (wv >= 4) {    // stage 1: waves 4-7 dump partials
        #pragma unroll
        for (int g = 0; g < 4; g++) {
            #pragma unroll
            for (int dt = 0; dt < 4; dt++)
                #pragma unroll
                for (int r = 0; r < 4; r++)
                    Mrg[wv - 4][g * 16 + 4 * quad + r][16 * dt + c] = oacc[g][dt][r];
            #pragma unroll
            for (int r = 0; r < 4; r++)
                Mrg[wv - 4][g * 16 + 4 * quad + r][64] = lacc[g][r];
        }
    }
    __syncthreads();
    if (wv < 4) {     // stage 2: fold wave wv+4's partials in, dump combined
        #pragma unroll
        for (int g = 0; g < 4; g++) {
            #pragma unroll
            for (int dt = 0; dt < 4; dt++)
                #pragma unroll
                for (int r = 0; r < 4; r++)
                    oacc[g][dt][r] += Mrg[wv][g * 16 + 4 * quad + r][16 * dt + c];
            #pragma unroll
            for (int r = 0; r < 4; r++)
                lacc[g][r] += Mrg[wv][g * 16 + 4 * quad + r][64];
        }
        #pragma unroll
        for (int g = 0; g < 4; g++) {
            #pragma unroll
            for (int dt = 0; dt < 4; dt++)
                #pragma unroll
                for (int r = 0; r < 4; r++)
                    Mrg[wv][g * 16 + 4 * quad + r][16 * dt + c] = oacc[g][dt][r];
            #pragma unroll
            for (int r = 0; r < 4; r++)
                Mrg[wv][g * 16 + 4 * quad + r][64] = lacc[g][r];
        }
    }
    __syncthreads();
    if (wv < 4) {     // final merge: wave wv owns rows 16wv..16wv+15
        const int row = 16 * wv + c;
        float sum[16];
        #pragma unroll
        for (int j = 0; j < 16; j++) sum[j] = 0.f;
        float lsum = 0.f;
        #pragma unroll
        for (int ws = 0; ws < 4; ws++) {
            #pragma unroll
            for (int j = 0; j < 16; j++) sum[j] += Mrg[ws][row][16 * quad + j];
            lsum += Mrg[ws][row][64];
        }
        float inv = 1.f / lsum;
        unsigned short us[16];
        #pragma unroll
        for (int j = 0; j < 16; j++) us[j] = f2bf(sum[j] * inv);
        unsigned short* xp =
            X + ((size_t)(b * 256 + qt * 64 + row)) * 512 + h * 64 + 16 * quad;
        *(uint4*)(xp)     = *(uint4*)&us[0];
        *(uint4*)(xp + 8) = *(uint4*)&us[8];
    }
}

// ---------------------------------------------------------------------------
extern "C" void kernel_launch(void* const* d_in, const int* in_sizes, int n_in,
                              void* d_out, int out_size, void* d_ws, size_t ws_size,
                              hipStream_t stream) {
    const float* Lmat = (const float*)d_in[0];  // [16,2048,512]
    const float* G    = (const float*)d_in[1];  // [16,256,512]
    const float* Wq   = (const float*)d_in[2];  // [512,512]
    const float* bq   = (const float*)d_in[3];  // [512]
    const float* Wo   = (const float*)d_in[4];  // [512,512]
    const float* bo   = (const float*)d_in[5];  // [512]
    float* out = (float*)d_out;                 // [16,256,512] f32

    const float SCe = 0.005524271728019903f * 1.4426950408889634f;  // scale*log2e

    // ws layout (bf16 elems): Qws 2M (unused) | Xws 2M | WqF 256K | WoF 256K | KF 16M | VF 16M
    unsigned short* Qws = (unsigned short*)d_ws;
    unsigned short* Xws = Qws + (size_t)2097152;
    unsigned short* WqF = Xws + (size_t)2097152;
    unsigned short* WoF = WqF + (size_t)262144;
    unsigned short* KF  = WoF + (size_t)262144;
    unsigned short* VF  = KF  + (size_t)16777216;

    conv_prep<<<4352, 256, 0, stream>>>(Lmat, Wq, Wo, KF, VF, WqF, WoF);
    attn_frag<<<512, 512, 0, stream>>>(G, WqF, bq, KF, VF, Xws, SCe);
    gemm_direct<true, false><<<dim3(64, 8), 256, 0, stream>>>(Xws, WoF, bo, out, 1.0f);
}

// Round 12
// 163.852 us; speedup vs baseline: 1.5270x; 1.5270x over previous
//
#include <hip/hip_runtime.h>

// B=16, Lk=2048, Lq=256, DIM=512, HEADS=8, d_k=64 — f32 I/O, bf16 MFMA internally.
// out = softmax((G@Wq+bq) heads @ L^T * scale) @ L, merge heads, @ Wo + bo
#define KSTR 72   // attn P-buffer row stride (shorts)

typedef __attribute__((ext_vector_type(8))) short short8;  // 8 bf16 (4 VGPRs)
typedef __attribute__((ext_vector_type(4))) float f32x4;

#define EXP2F(x) __builtin_amdgcn_exp2f(x)

__device__ __forceinline__ unsigned short f2bf(float f) {   // RNE f32->bf16
    union { float f; unsigned u; } v; v.f = f;
    unsigned r = v.u + 0x7fff + ((v.u >> 16) & 1);
    return (unsigned short)(r >> 16);
}
__device__ __forceinline__ unsigned pk2(float a, float b) {
    return (unsigned)f2bf(a) | ((unsigned)f2bf(b) << 16);
}

// ---- merged prep: blocks [0,4096) do conv_L; blocks [4096,4352) do conv_W.
__global__ __launch_bounds__(256) void conv_prep(const float* __restrict__ Lmat,
                                                 const float* __restrict__ Wq,
                                                 const float* __restrict__ Wo,
                                                 unsigned short* __restrict__ KF,
                                                 unsigned short* __restrict__ VF,
                                                 unsigned short* __restrict__ WqF,
                                                 unsigned short* __restrict__ WoF) {
    const int tid = threadIdx.x;
    if (blockIdx.x >= 4096) {
        const int idx = blockIdx.x - 4096;            // [0,256)
        const float* W = (idx >> 7) ? Wo : Wq;
        unsigned short* WF = (idx >> 7) ? WoF : WqF;
        int g = (idx & 127) * 256 + tid;              // [0, 32768)
        int lane = g & 63, ntg = (g >> 6) & 31, kt = g >> 11;
        int c = lane & 15, quad = lane >> 4;
        const float* wp = W + (size_t)(32 * kt + 8 * quad) * 512 + 16 * ntg + c;
        float v[8];
        #pragma unroll
        for (int j = 0; j < 8; j++) v[j] = wp[(size_t)j * 512];
        uint4 u;
        u.x = pk2(v[0], v[1]); u.y = pk2(v[2], v[3]);
        u.z = pk2(v[4], v[5]); u.w = pk2(v[6], v[7]);
        *(uint4*)(WF + (size_t)g * 8) = u;
        return;
    }
    __shared__ unsigned short KFs[4096];
    __shared__ unsigned short VFs[4096];
    const int blk = blockIdx.x;            // ((b*8+h)*32+t)
    const int t = blk & 31, h = (blk >> 5) & 7, b = blk >> 8;
    const int key = tid & 63, wv = tid >> 6;   // 16 d's per thread

    const float* src = Lmat + ((size_t)(b * 2048 + 64 * t + key)) * 512 + 64 * h + 16 * wv;
    float4 a0 = *(const float4*)src;
    float4 a1 = *(const float4*)(src + 4);
    float4 a2 = *(const float4*)(src + 8);
    float4 a3 = *(const float4*)(src + 12);
    float vals[16] = {a0.x, a0.y, a0.z, a0.w, a1.x, a1.y, a1.z, a1.w,
                      a2.x, a2.y, a2.z, a2.w, a3.x, a3.y, a3.z, a3.w};
    #pragma unroll
    for (int i = 0; i < 16; i++) {
        int d = 16 * wv + i;
        unsigned short bv = f2bf(vals[i]);
        KFs[((((key >> 4) * 2 + (d >> 5)) * 64) + ((d >> 3) & 3) * 16 + (key & 15)) * 8 + (d & 7)] = bv;
        VFs[((((d >> 4) * 2 + (key >> 5)) * 64) + ((key >> 3) & 3) * 16 + (d & 15)) * 8 + (key & 7)] = bv;
    }
    __syncthreads();
    size_t gbase = (size_t)blk * 4096 + tid * 16;
    *(uint4*)(KF + gbase)     = *(const uint4*)&KFs[tid * 16];
    *(uint4*)(KF + gbase + 8) = *(const uint4*)&KFs[tid * 16 + 8];
    *(uint4*)(VF + gbase)     = *(const uint4*)&VFs[tid * 16];
    *(uint4*)(VF + gbase + 8) = *(const uint4*)&VFs[tid * 16 + 8];
}

// ---- barrier-free gemm: C[M,512] = (A@W + bias)*oscale. No LDS, no syncs.
template<bool A_BF16, bool OUT_BF16>
__global__ __launch_bounds__(256, 2) void gemm_direct(const void* __restrict__ Ap,
                                                      const unsigned short* __restrict__ WF,
                                                      const float* __restrict__ bias,
                                                      void* __restrict__ Cp,
                                                      float oscale) {
    const int tid = threadIdx.x;
    const int wv = tid >> 6, lane = tid & 63;
    const int c = lane & 15, quad = lane >> 4;
    const int m0 = blockIdx.x * 64, n0 = blockIdx.y * 64;
    const int row = m0 + 16 * wv + c;

    f32x4 acc[4];
    #pragma unroll
    for (int nt = 0; nt < 4; nt++) acc[nt] = (f32x4){0.f, 0.f, 0.f, 0.f};

    #pragma unroll
    for (int kk = 0; kk < 16; kk++) {
        short8 af;
        if (A_BF16) {
            af = *(const short8*)((const unsigned short*)Ap + (size_t)row * 512 + 32 * kk + 8 * quad);
        } else {
            const float* ap = (const float*)Ap + (size_t)row * 512 + 32 * kk + 8 * quad;
            float4 x0 = *(const float4*)ap;
            float4 x1 = *(const float4*)(ap + 4);
            af[0] = (short)f2bf(x0.x); af[1] = (short)f2bf(x0.y);
            af[2] = (short)f2bf(x0.z); af[3] = (short)f2bf(x0.w);
            af[4] = (short)f2bf(x1.x); af[5] = (short)f2bf(x1.y);
            af[6] = (short)f2bf(x1.z); af[7] = (short)f2bf(x1.w);
        }
        #pragma unroll
        for (int nt = 0; nt < 4; nt++) {
            short8 bf = *(const short8*)(WF +
                (((size_t)kk * 32 + (n0 >> 4) + nt) * 64 + lane) * 8);
            acc[nt] = __builtin_amdgcn_mfma_f32_16x16x32_bf16(af, bf, acc[nt], 0, 0, 0);
        }
    }

    #pragma unroll
    for (int nt = 0; nt < 4; nt++) {
        float bv = bias[n0 + 16 * nt + c];
        #pragma unroll
        for (int r = 0; r < 4; r++) {
            float v = (acc[nt][r] + bv) * oscale;
            size_t idx = (size_t)(m0 + 16 * wv + 4 * quad + r) * 512 + n0 + 16 * nt + c;
            if (OUT_BF16) ((unsigned short*)Cp)[idx] = f2bf(v);
            else          ((float*)Cp)[idx] = v;
        }
    }
}

// ---- attn (round-7 structure, best measured: attn 41.3us / e2e 164.3) with
// ROTATED K/V loads. Closed avenues (measured): reordering (R0-3 null), coop
// LDS staging (R8 -32%), wave-private LDS ring (R9 -5%), finer q-tiles (R10
// -25%, traffic x2), >2 waves/SIMD (R4/R11 spill: body needs ~104 regs).
// Remaining exposed cost: K's load->use gap was ZERO (loads at loop top, QK
// immediately after) while V's ~700cy gap is covered. Rotation (plain loads,
// compiler-managed waits -> correct by construction, +0 regs):
//   prologue: K(wv),V(wv) issued BEFORE Q-proj (~4k cy cover for coldest tile)
//   loop: QK/exp uses kbuf -> reload kbuf=K(T+4) (cover = PV ~350cy)
//         PV uses vbuf      -> reload vbuf=V(T+4) (cover = next QK+exp ~700cy)
__global__ __launch_bounds__(256, 2) void attn_frag(const float* __restrict__ G,
                                                    const unsigned short* __restrict__ WqF,
                                                    const float* __restrict__ bq,
                                                    const unsigned short* __restrict__ KF,
                                                    const unsigned short* __restrict__ VF,
                                                    unsigned short* __restrict__ X,
                                                    float SCe) {
    // Overlay: [0,36864) Pw shorts | [36864,46080) Qs shorts  (loop phase)
    //          [0,69632) Mrg f32                               (merge phase)
    __shared__ __align__(16) char shm_raw[4 * 64 * 68 * 4];
    unsigned short (*Pw)[4][16 * KSTR] = (unsigned short (*)[4][16 * KSTR])shm_raw;
    unsigned short (*Qs)[72] = (unsigned short (*)[72])(shm_raw + 36864);
    float (*Mrg)[64][68] = (float (*)[64][68])shm_raw;

    // swizzle: raw = xcd + 8*(qt + 4*grp); bh = grp*8 + xcd -> b=grp, h=xcd
    const int raw = blockIdx.x;
    const int h  = raw & 7;
    const int qt = (raw >> 3) & 3;
    const int b  = raw >> 5;
    const int tid = threadIdx.x;
    const int wv = tid >> 6, lane = tid & 63;
    const int c = lane & 15, quad = lane >> 4;
    const int n0 = h * 64;

    const unsigned short* kf = KF + ((size_t)((b * 8 + h) * 32)) * 4096 + lane * 8;
    const unsigned short* vf = VF + ((size_t)((b * 8 + h) * 32)) * 4096 + lane * 8;

    // prologue loads: tile wv's K/V issued before Q-proj (compiler waits at use)
    short8 kbuf[8], vbuf[8];
    {
        const unsigned short* kt0 = kf + (size_t)wv * 4096;
        const unsigned short* vt0 = vf + (size_t)wv * 4096;
        #pragma unroll
        for (int f = 0; f < 8; f++) kbuf[f] = *(const short8*)(kt0 + f * 512);
        #pragma unroll
        for (int f = 0; f < 8; f++) vbuf[f] = *(const short8*)(vt0 + f * 512);
    }

    // ---- fused Q projection (same frag math as gemm_direct<false,true>)
    {
        f32x4 qacc[4];
        #pragma unroll
        for (int nt = 0; nt < 4; nt++) qacc[nt] = (f32x4){0.f, 0.f, 0.f, 0.f};
        const float* gbase = G + ((size_t)(b * 256 + qt * 64 + 16 * wv + c)) * 512;
        #pragma unroll
        for (int kk = 0; kk < 16; kk++) {
            const float* ap = gbase + 32 * kk + 8 * quad;
            float4 x0 = *(const float4*)ap;
            float4 x1 = *(const float4*)(ap + 4);
            short8 af;
            af[0] = (short)f2bf(x0.x); af[1] = (short)f2bf(x0.y);
            af[2] = (short)f2bf(x0.z); af[3] = (short)f2bf(x0.w);
            af[4] = (short)f2bf(x1.x); af[5] = (short)f2bf(x1.y);
            af[6] = (short)f2bf(x1.z); af[7] = (short)f2bf(x1.w);
            #pragma unroll
            for (int nt = 0; nt < 4; nt++) {
                short8 bf = *(const short8*)(WqF +
                    (((size_t)kk * 32 + (n0 >> 4) + nt) * 64 + lane) * 8);
                qacc[nt] = __builtin_amdgcn_mfma_f32_16x16x32_bf16(af, bf, qacc[nt], 0, 0, 0);
            }
        }
        #pragma unroll
        for (int nt = 0; nt < 4; nt++) {
            float bv = bq[n0 + 16 * nt + c];
            #pragma unroll
            for (int r = 0; r < 4; r++)
                Qs[16 * wv + 4 * quad + r][16 * nt + c] =
                    f2bf((qacc[nt][r] + bv) * SCe);
        }
    }
    __syncthreads();

    short8 qa[4][2];   // all 64 q-rows: qgrp g = rows 16g..16g+15
    #pragma unroll
    for (int g = 0; g < 4; g++) {
        qa[g][0] = *(const short8*)&Qs[16 * g + c][8 * quad];
        qa[g][1] = *(const short8*)&Qs[16 * g + c][32 + 8 * quad];
    }

    short8 ones;
    #pragma unroll
    for (int i = 0; i < 8; i++) ones[i] = (short)0x3F80;

    f32x4 oacc[4][4];
    #pragma unroll
    for (int g = 0; g < 4; g++)
        #pragma unroll
        for (int dt = 0; dt < 4; dt++) oacc[g][dt] = (f32x4){0.f, 0.f, 0.f, 0.f};
    f32x4 lacc[4];
    #pragma unroll
    for (int g = 0; g < 4; g++) lacc[g] = (f32x4){0.f, 0.f, 0.f, 0.f};

    const int swc = (c >> 3) & 1;
    const int swr = (quad >> 1) & 1;

    for (int i = 0; i < 8; i++) {
        const int T = wv + 4 * i;           // this wave's tile

        // QK + P-store for all 4 q-groups (consumes kbuf)
        #pragma unroll
        for (int g = 0; g < 4; g++) {
            f32x4 sacc[4];
            #pragma unroll
            for (int nt = 0; nt < 4; nt++) sacc[nt] = (f32x4){0.f, 0.f, 0.f, 0.f};
            __builtin_amdgcn_s_setprio(1);
            #pragma unroll
            for (int nt = 0; nt < 4; nt++)
                #pragma unroll
                for (int ks = 0; ks < 2; ks++)
                    sacc[nt] = __builtin_amdgcn_mfma_f32_16x16x32_bf16(
                        qa[g][ks], kbuf[nt * 2 + ks], sacc[nt], 0, 0, 0);
            __builtin_amdgcn_s_setprio(0);
            #pragma unroll
            for (int nt = 0; nt < 4; nt++)
                #pragma unroll
                for (int r = 0; r < 4; r++)
                    Pw[wv][g][(4 * quad + r) * KSTR + ((16 * nt + c) ^ (8 * swr))] =
                        f2bf(EXP2F(sacc[nt][r]));
        }

        // kbuf dead -> reload with K(T+4); waited at next iteration's QK,
        // covered by the PV phase below.
        if (i < 7) {
            const unsigned short* kt = kf + (size_t)(T + 4) * 4096;
            #pragma unroll
            for (int f = 0; f < 8; f++) kbuf[f] = *(const short8*)(kt + f * 512);
        }

        // PV for all 4 q-groups (consumes vbuf)
        #pragma unroll
        for (int g = 0; g < 4; g++) {
            short8 pa0 = *(const short8*)&Pw[wv][g][c * KSTR + 8 * (quad ^ swc)];
            short8 pa1 = *(const short8*)&Pw[wv][g][c * KSTR + 32 + 8 * (quad ^ swc)];
            __builtin_amdgcn_s_setprio(1);
            #pragma unroll
            for (int dt = 0; dt < 4; dt++) {
                oacc[g][dt] = __builtin_amdgcn_mfma_f32_16x16x32_bf16(pa0, vbuf[dt * 2], oacc[g][dt], 0, 0, 0);
                oacc[g][dt] = __builtin_amdgcn_mfma_f32_16x16x32_bf16(pa1, vbuf[dt * 2 + 1], oacc[g][dt], 0, 0, 0);
            }
            lacc[g] = __builtin_amdgcn_mfma_f32_16x16x32_bf16(pa0, ones, lacc[g], 0, 0, 0);
            lacc[g] = __builtin_amdgcn_mfma_f32_16x16x32_bf16(pa1, ones, lacc[g], 0, 0, 0);
            __builtin_amdgcn_s_setprio(0);
        }

        // vbuf dead -> reload with V(T+4); waited at next iteration's PV,
        // covered by next QK + exp phases.
        if (i < 7) {
            const unsigned short* vt = vf + (size_t)(T + 4) * 4096;
            #pragma unroll
            for (int f = 0; f < 8; f++) vbuf[f] = *(const short8*)(vt + f * 512);
        }
    }

    // ---- additive split-K merge (Mrg overlays Pw/Qs -> barrier first).
    __syncthreads();
    #pragma unroll
    for (int g = 0; g < 4; g++) {
        #pragma unroll
        for (int dt = 0; dt < 4; dt++)
            #pragma unroll
            for (int r = 0; r < 4; r++)
                Mrg[wv][g * 16 + 4 * quad + r][16 * dt + c] = oacc[g][dt][r];
        #pragma unroll
        for (int r = 0; r < 4; r++)
            Mrg[wv][g * 16 + 4 * quad + r][64] = lacc[g][r];   // all c same value
    }
    __syncthreads();
    {
        const int row = 16 * wv + c;   // merge-wave wv owns rows 16wv..16wv+15
        float sum[16];
        #pragma unroll
        for (int j = 0; j < 16; j++) sum[j] = 0.f;
        float lsum = 0.f;
        #pragma unroll
        for (int ws = 0; ws < 4; ws++) {
            #pragma unroll
            for (int j = 0; j < 16; j++) sum[j] += Mrg[ws][row][16 * quad + j];
            lsum += Mrg[ws][row][64];
        }
        float inv = 1.f / lsum;
        unsigned short us[16];
        #pragma unroll
        for (int j = 0; j < 16; j++) us[j] = f2bf(sum[j] * inv);
        unsigned short* xp =
            X + ((size_t)(b * 256 + qt * 64 + row)) * 512 + h * 64 + 16 * quad;
        *(uint4*)(xp)     = *(uint4*)&us[0];
        *(uint4*)(xp + 8) = *(uint4*)&us[8];
    }
}

// ---------------------------------------------------------------------------
extern "C" void kernel_launch(void* const* d_in, const int* in_sizes, int n_in,
                              void* d_out, int out_size, void* d_ws, size_t ws_size,
                              hipStream_t stream) {
    const float* Lmat = (const float*)d_in[0];  // [16,2048,512]
    const float* G    = (const float*)d_in[1];  // [16,256,512]
    const float* Wq   = (const float*)d_in[2];  // [512,512]
    const float* bq   = (const float*)d_in[3];  // [512]
    const float* Wo   = (const float*)d_in[4];  // [512,512]
    const float* bo   = (const float*)d_in[5];  // [512]
    float* out = (float*)d_out;                 // [16,256,512] f32

    const float SCe = 0.005524271728019903f * 1.4426950408889634f;  // scale*log2e

    // ws layout (bf16 elems): Qws 2M (unused) | Xws 2M | WqF 256K | WoF 256K | KF 16M | VF 16M
    unsigned short* Qws = (unsigned short*)d_ws;
    unsigned short* Xws = Qws + (size_t)2097152;
    unsigned short* WqF = Xws + (size_t)2097152;
    unsigned short* WoF = WqF + (size_t)262144;
    unsigned short* KF  = WoF + (size_t)262144;
    unsigned short* VF  = KF  + (size_t)16777216;

    conv_prep<<<4352, 256, 0, stream>>>(Lmat, Wq, Wo, KF, VF, WqF, WoF);
    attn_frag<<<512, 256, 0, stream>>>(G, WqF, bq, KF, VF, Xws, SCe);
    gemm_direct<true, false><<<dim3(64, 8), 256, 0, stream>>>(Xws, WoF, bo, out, 1.0f);
}